// Round 5
// baseline (368.394 us; speedup 1.0000x reference)
//
#include <hip/hip_runtime.h>
#include <hip/hip_bf16.h>

#define BB 512
#define VV 6890
#define NJ 24
#define NBETA 10
#define NP 207           // (24-1)*9
#define KK 217           // NP + NBETA (betas folded into the GEMM)
#define N3 (VV*3)        // 20670
#define PT_LD 36         // pfT row stride (16B-aligned b128 reads, conflict-light staging)
#define VBAT 8           // batch tile in k_verts

// d_out element offsets (fp32), concatenated in return order:
// verts (B,V,3), posed_joints (B,J,3), A (B,J,4,4), transforms (B,J,4,4), v_posed (B,V,3)
#define OFF_VERTS 0
#define OFF_PJ   (BB*VV*3)
#define OFF_A    (OFF_PJ + BB*NJ*3)
#define OFF_TF   (OFF_A + BB*NJ*16)
#define OFF_VP   (OFF_TF + BB*NJ*16)

// ws layout (fp32 elements) — ~2.1 MB
#define WS_JTJS 0                        // 24*33
#define WS_PF   (WS_JTJS + NJ*33)        // B*207
#define WS_A    (WS_PF + BB*NP)          // B*24*16
#define WS_SDT  (WS_A + BB*NJ*16)        // 10*N3 (shapedirs transposed)

__constant__ int c_par[NJ] = {-1, 0, 0, 0, 1, 2, 3, 4, 5, 6, 7, 8,
                              9, 9, 9, 12, 13, 14, 16, 17, 18, 19, 20, 21};

// ------------------------------------------------- K0: sdT[l][n] = sd[n][l]
__global__ void k_sdt(const float* __restrict__ sd, float* __restrict__ sdT) {
    int n = blockIdx.x * 256 + threadIdx.x;
    if (n >= N3) return;
#pragma unroll
    for (int l = 0; l < NBETA; l++)
        sdT[(size_t)l * N3 + n] = sd[n * NBETA + l];
}

// ------------------------------------------------- K1: JT = Jreg@vt, JS = Jreg@sd
__global__ void k_jreg(const float* __restrict__ jr,
                       const float* __restrict__ vt,
                       const float* __restrict__ sd,
                       float* __restrict__ ws) {
    int j = blockIdx.x / 33, idx = blockIdx.x % 33;
    int t = threadIdx.x;
    float acc = 0.f;
    for (int v = t; v < VV; v += 256) {
        float a = jr[j * VV + v];
        float x = (idx < 3) ? vt[v * 3 + idx] : sd[v * 30 + (idx - 3)];
        acc += a * x;
    }
    __shared__ float red[256];
    red[t] = acc;
    __syncthreads();
    for (int s = 128; s > 0; s >>= 1) {
        if (t < s) red[t] += red[t + s];
        __syncthreads();
    }
    if (t == 0) ws[WS_JTJS + j * 33 + idx] = red[0];
}

// ------------------------------- K2: Jloc, Rodrigues, chain, A/transforms/joints
__global__ __launch_bounds__(64) void k_chain(
        const float* __restrict__ betas,
        const float* __restrict__ pose,
        const float* __restrict__ ws_jtjs,
        float* __restrict__ ws_pf,
        float* __restrict__ ws_A,
        float* __restrict__ out) {
    int b = blockIdx.x;
    int t = threadIdx.x;
    __shared__ float Jl[NJ][3];
    __shared__ float tm[NJ][16];
    __shared__ float ch[NJ][16];
    float R[9];

    if (t < NJ) {
        int j = t;
        float bb[NBETA];
#pragma unroll
        for (int l = 0; l < NBETA; l++) bb[l] = betas[b * NBETA + l];
#pragma unroll
        for (int k = 0; k < 3; k++) {
            float acc = ws_jtjs[j * 33 + k];
#pragma unroll
            for (int l = 0; l < NBETA; l++) acc += bb[l] * ws_jtjs[j * 33 + 3 + k * NBETA + l];
            Jl[j][k] = acc;
        }
        float ax = pose[b * NJ * 3 + j * 3 + 0];
        float ay = pose[b * NJ * 3 + j * 3 + 1];
        float az = pose[b * NJ * 3 + j * 3 + 2];
        float e0 = ax + 1e-8f, e1 = ay + 1e-8f, e2 = az + 1e-8f;
        float ang = sqrtf(e0 * e0 + e1 * e1 + e2 * e2);
        float inv = 1.f / ang;
        float rx = ax * inv, ry = ay * inv, rz = az * inv;
        float sn = sinf(ang), cs = cosf(ang);
        float Km[9] = {0.f, -rz, ry, rz, 0.f, -rx, -ry, rx, 0.f};
#pragma unroll
        for (int r = 0; r < 3; r++)
#pragma unroll
            for (int c = 0; c < 3; c++) {
                float kk = Km[3 * r + 0] * Km[0 + c] + Km[3 * r + 1] * Km[3 + c] +
                           Km[3 * r + 2] * Km[6 + c];
                R[3 * r + c] = ((r == c) ? 1.f : 0.f) + sn * Km[3 * r + c] + (1.f - cs) * kk;
            }
        if (j >= 1) {
#pragma unroll
            for (int e = 0; e < 9; e++) {
                int r = e / 3, c = e % 3;
                ws_pf[b * NP + (j - 1) * 9 + e] = R[e] - ((r == c) ? 1.f : 0.f);
            }
        }
    }
    __syncthreads();
    if (t < NJ) {
        int j = t;
        int p = c_par[j];
        int ps = (p < 0) ? 0 : p;
#pragma unroll
        for (int r = 0; r < 3; r++) {
            tm[j][r * 4 + 0] = R[3 * r + 0];
            tm[j][r * 4 + 1] = R[3 * r + 1];
            tm[j][r * 4 + 2] = R[3 * r + 2];
            tm[j][r * 4 + 3] = (j == 0) ? Jl[j][r] : (Jl[j][r] - Jl[ps][r]);
        }
        tm[j][12] = 0.f; tm[j][13] = 0.f; tm[j][14] = 0.f; tm[j][15] = 1.f;
    }
    __syncthreads();
    if (t < 16) ch[0][t] = tm[0][t];
    __syncthreads();
    for (int i = 1; i < NJ; i++) {
        if (t < 16) {
            int r = t >> 2, c = t & 3;
            int p = c_par[i];
            ch[i][t] = ch[p][4 * r + 0] * tm[i][0 + c] + ch[p][4 * r + 1] * tm[i][4 + c] +
                       ch[p][4 * r + 2] * tm[i][8 + c] + ch[p][4 * r + 3] * tm[i][12 + c];
        }
        __syncthreads();
    }
    if (t < NJ) {
        int j = t;
        float ib[4];
#pragma unroll
        for (int p = 0; p < 4; p++)
            ib[p] = ch[j][4 * p + 0] * Jl[j][0] + ch[j][4 * p + 1] * Jl[j][1] +
                    ch[j][4 * p + 2] * Jl[j][2];
#pragma unroll
        for (int e = 0; e < 16; e++) {
            int r = e >> 2, c = e & 3;
            float tr = ch[j][e];
            float Ae = tr - ((c == 3) ? ib[r] : 0.f);
            out[OFF_TF + (size_t)(b * NJ + j) * 16 + e] = tr;
            out[OFF_A + (size_t)(b * NJ + j) * 16 + e] = Ae;
            ws_A[(size_t)(b * NJ + j) * 16 + e] = Ae;
        }
#pragma unroll
        for (int k = 0; k < 3; k++)
            out[OFF_PJ + (size_t)(b * NJ + j) * 3 + k] = ch[j][4 * k + 3];
    }
}

// ----------- K3: v_posed[b,n] = vt[n] + [pf|betas][b,:] @ [pd; sdT][:,n]
// Register GEMM: block = 32 b x 256 n, thread = 8 b x 4 n, weights via
// wave-uniform ds_read_b128 from transposed LDS tile.
__global__ __launch_bounds__(256) void k_posed(
        const float* __restrict__ vt,
        const float* __restrict__ betas,
        const float* __restrict__ pd,
        const float* __restrict__ ws_pf,
        const float* __restrict__ sdT,
        float* __restrict__ out) {
    __shared__ __align__(16) float pfT[KK][PT_LD];
    int b0 = blockIdx.y * 32;
    int tid = threadIdx.x;
    // stage transposed weights: pfT[k][b] = k<207 ? pf[b0+b][k] : betas[b0+b][k-207]
    for (int idx = tid; idx < 32 * KK; idx += 256) {
        int b = idx / KK, k = idx % KK;
        float w = (k < NP) ? ws_pf[(size_t)(b0 + b) * NP + k]
                           : betas[(size_t)(b0 + b) * NBETA + (k - NP)];
        pfT[k][b] = w;
    }
    __syncthreads();

    int lane = tid & 63;
    int woff = (tid >> 6) * 8;                // wave's 8-batch slice
    int n0 = blockIdx.x * 256 + lane * 4;
    if (n0 >= N3) return;

    float acc[8][4];
#pragma unroll
    for (int bi = 0; bi < 8; bi++)
#pragma unroll
        for (int c = 0; c < 4; c++) acc[bi][c] = 0.f;

    if (n0 + 4 <= N3) {                        // fast path: full float4
        auto step = [&](const float* __restrict__ row, int k) {
            const float4 pv = *(const float4*)(row + n0);
            const float4 wa = *(const float4*)&pfT[k][woff];
            const float4 wb = *(const float4*)&pfT[k][woff + 4];
            const float wv[8] = {wa.x, wa.y, wa.z, wa.w, wb.x, wb.y, wb.z, wb.w};
#pragma unroll
            for (int bi = 0; bi < 8; bi++) {
                acc[bi][0] += wv[bi] * pv.x;
                acc[bi][1] += wv[bi] * pv.y;
                acc[bi][2] += wv[bi] * pv.z;
                acc[bi][3] += wv[bi] * pv.w;
            }
        };
        for (int k = 0; k < NP; k++) step(pd + (size_t)k * N3, k);
#pragma unroll
        for (int l = 0; l < NBETA; l++) step(sdT + (size_t)l * N3, NP + l);

        const float4 vtv = *(const float4*)(vt + n0);
#pragma unroll
        for (int bi = 0; bi < 8; bi++) {
            float4 o;
            o.x = acc[bi][0] + vtv.x;
            o.y = acc[bi][1] + vtv.y;
            o.z = acc[bi][2] + vtv.z;
            o.w = acc[bi][3] + vtv.w;
            *(float4*)&out[OFF_VP + (size_t)(b0 + woff + bi) * N3 + n0] = o;
        }
    } else {                                   // tail: scalar, guarded
        int nv = N3 - n0;                      // 1..3
        auto step = [&](const float* __restrict__ row, int k) {
            float pv[4] = {0.f, 0.f, 0.f, 0.f};
            for (int c = 0; c < nv; c++) pv[c] = row[n0 + c];
            const float4 wa = *(const float4*)&pfT[k][woff];
            const float4 wb = *(const float4*)&pfT[k][woff + 4];
            const float wv[8] = {wa.x, wa.y, wa.z, wa.w, wb.x, wb.y, wb.z, wb.w};
#pragma unroll
            for (int bi = 0; bi < 8; bi++)
#pragma unroll
                for (int c = 0; c < 4; c++) acc[bi][c] += wv[bi] * pv[c];
        };
        for (int k = 0; k < NP; k++) step(pd + (size_t)k * N3, k);
        for (int l = 0; l < NBETA; l++) step(sdT + (size_t)l * N3, NP + l);
        for (int bi = 0; bi < 8; bi++)
            for (int c = 0; c < nv; c++)
                out[OFF_VP + (size_t)(b0 + woff + bi) * N3 + n0 + c] =
                    acc[bi][c] + vt[n0 + c];
    }
}

// --------------------------------------------- K4: verts = (lw@A) . [vposed,1]
// A staged in LDS (VBAT batches), rows read wave-uniform b128 and reused
// across the batch loop; 3 accumulators per batch instead of 12.
__global__ __launch_bounds__(256) void k_verts(
        const float* __restrict__ lw,
        const float* __restrict__ ws_A,
        float* __restrict__ out) {
    __shared__ __align__(16) float As[VBAT][NJ][16];
    int b0 = blockIdx.y * VBAT;
    int tid = threadIdx.x;
    for (int idx = tid; idx < VBAT * NJ * 4; idx += 256) {   // 768 float4 copies
        const float4 f = *(const float4*)&ws_A[(size_t)b0 * NJ * 16 + idx * 4];
        *(float4*)&((float*)As)[idx * 4] = f;
    }
    __syncthreads();
    int v = blockIdx.x * 256 + tid;
    if (v >= VV) return;

    float w[NJ];
#pragma unroll
    for (int q = 0; q < NJ / 4; q++) {
        const float4 f = *(const float4*)&lw[(size_t)v * NJ + q * 4];
        w[q * 4 + 0] = f.x; w[q * 4 + 1] = f.y; w[q * 4 + 2] = f.z; w[q * 4 + 3] = f.w;
    }
    float xyz[VBAT][3], acc[VBAT][3];
#pragma unroll
    for (int bi = 0; bi < VBAT; bi++) {
        size_t base = OFF_VP + (size_t)((b0 + bi) * VV + v) * 3;
        xyz[bi][0] = out[base + 0];
        xyz[bi][1] = out[base + 1];
        xyz[bi][2] = out[base + 2];
        acc[bi][0] = 0.f; acc[bi][1] = 0.f; acc[bi][2] = 0.f;
    }
    for (int j = 0; j < NJ; j++) {
        float wj = w[j];
        const float4 r0 = *(const float4*)&As[0][j][0];      // rows shared across bi?
#pragma unroll
        for (int bi = 0; bi < VBAT; bi++) {
            const float4 a0 = *(const float4*)&As[bi][j][0];
            const float4 a1 = *(const float4*)&As[bi][j][4];
            const float4 a2 = *(const float4*)&As[bi][j][8];
            acc[bi][0] += wj * (a0.x * xyz[bi][0] + a0.y * xyz[bi][1] + a0.z * xyz[bi][2] + a0.w);
            acc[bi][1] += wj * (a1.x * xyz[bi][0] + a1.y * xyz[bi][1] + a1.z * xyz[bi][2] + a1.w);
            acc[bi][2] += wj * (a2.x * xyz[bi][0] + a2.y * xyz[bi][1] + a2.z * xyz[bi][2] + a2.w);
        }
        (void)r0;
    }
#pragma unroll
    for (int bi = 0; bi < VBAT; bi++) {
        size_t base = OFF_VERTS + (size_t)((b0 + bi) * VV + v) * 3;
        out[base + 0] = acc[bi][0];
        out[base + 1] = acc[bi][1];
        out[base + 2] = acc[bi][2];
    }
}

extern "C" void kernel_launch(void* const* d_in, const int* in_sizes, int n_in,
                              void* d_out, int out_size, void* d_ws, size_t ws_size,
                              hipStream_t stream) {
    const float* betas = (const float*)d_in[0];
    const float* pose  = (const float*)d_in[1];
    const float* vt    = (const float*)d_in[2];
    const float* sd    = (const float*)d_in[3];
    const float* pd    = (const float*)d_in[4];
    const float* jr    = (const float*)d_in[5];
    const float* lw    = (const float*)d_in[6];
    float* out = (float*)d_out;
    float* ws = (float*)d_ws;

    k_sdt<<<(N3 + 255) / 256, 256, 0, stream>>>(sd, ws + WS_SDT);
    k_jreg<<<NJ * 33, 256, 0, stream>>>(jr, vt, sd, ws);
    k_chain<<<BB, 64, 0, stream>>>(betas, pose, ws + WS_JTJS, ws + WS_PF,
                                   ws + WS_A, out);
    k_posed<<<dim3((N3 + 255) / 256, BB / 32), 256, 0, stream>>>(
        vt, betas, pd, ws + WS_PF, ws + WS_SDT, out);
    k_verts<<<dim3((VV + 255) / 256, BB / VBAT), 256, 0, stream>>>(
        lw, ws + WS_A, out);
}